// Round 2
// baseline (379.100 us; speedup 1.0000x reference)
//
#include <hip/hip_runtime.h>
#include <hip/hip_bf16.h>

// MultiAgentSEPSNetwork: A=8 agents, E=4096, O=256, H1=H2=1024, H3=512, S=4.
// M = A*E = 32768 rows. Only the seps_idx-selected net per agent is computed
// (reference computes all S then gathers -> we skip 4x FLOPs).
//
// R2 changes vs R1 (587 TF on L2 GEMM, MfmaUtil 24%, 8.4M LDS conflict cyc):
//  - chunked LDS layout [rowgrp][kq][l16][8] -> fragment ds_read_b128 is
//    contiguous 1KB/wave => bank-conflict-free (R1 row-major 64B-stride reads
//    hit 2 banks per 8-lane group).
//  - BK=64: half the barriers (32 MFMA per sync). LDS 32KB, occupancy still
//    register-limited at ~3 blocks/CU.
//  - grid n-fastest for A-tile L2 reuse.

typedef unsigned short u16;
typedef __bf16 bf16x8 __attribute__((ext_vector_type(8)));
typedef float floatx4 __attribute__((ext_vector_type(4)));

__device__ __forceinline__ u16 f2bf(float f) {
    union { float f; unsigned int u; } v; v.f = f;
    unsigned int u = v.u;
    return (u16)((u + 0x7FFFu + ((u >> 16) & 1u)) >> 16);
}

// global -> LDS direct DMA, 16 B/lane. LDS dest = wave-uniform base + lane*16;
// per-lane GLOBAL address is arbitrary -> we use it to swizzle the layout.
__device__ __forceinline__ void load16(const void* g, void* l) {
    __builtin_amdgcn_global_load_lds(
        (const __attribute__((address_space(1))) void*)(unsigned long long)g,
        (__attribute__((address_space(3))) void*)(unsigned int)(unsigned long long)l,
        16, 0, 0);
}

// ---------------- conversion kernels ----------------

__global__ void convert_f32_bf16(const float* __restrict__ src,
                                 u16* __restrict__ dst, int n) {
    int i = (blockIdx.x * blockDim.x + threadIdx.x) * 4;
    if (i < n) {
        float4 v = *(const float4*)(src + i);
        ushort4 o;
        o.x = f2bf(v.x); o.y = f2bf(v.y); o.z = f2bf(v.z); o.w = f2bf(v.w);
        *(ushort4*)(dst + i) = o;
    }
}

// [S][K][N] f32 -> [S][N][K] bf16 weight transpose (k contiguous per out row).
__global__ void transpose_to_bf16(const float* __restrict__ src,
                                  u16* __restrict__ dst, int K, int N) {
    __shared__ float tile[32][33];
    int s = blockIdx.z;
    src += (size_t)s * K * N;
    dst += (size_t)s * N * K;
    int n0 = blockIdx.x * 32, k0 = blockIdx.y * 32;
    int tx = threadIdx.x, ty = threadIdx.y;
#pragma unroll
    for (int j = 0; j < 32; j += 8)
        tile[ty + j][tx] = src[(size_t)(k0 + ty + j) * N + (n0 + tx)];
    __syncthreads();
#pragma unroll
    for (int j = 0; j < 32; j += 8)
        dst[(size_t)(n0 + ty + j) * K + (k0 + tx)] = f2bf(tile[tx][ty + j]);
}

// ---------------- grouped GEMM ----------------
// C[m,n] = act(A[M,K] @ Wt[s][N,K]^T + bias[s][N]);  s = seps[agent(m)]
// 128x128 tile, BK=64, 256 thr = 4 waves (2x2), 64x64/wave, 16x16x32 MFMA.
//
// LDS layout (per tile, 16KB): chunk c (1KB) = [rowgrp g=c>>1][kq0=(c&1)*4]
//   within chunk: lane i -> [kq = i>>4][l16 = i&15][8 bf16]
// fragment read for (rowgrp m', k-half h): u16 idx = m'*1024 + h*512
//   + quad*128 + l16*8  -> contiguous 1KB per wave, conflict-free.
template <int K, int N, bool RELU, bool OUT_BF16>
__global__ __launch_bounds__(256) void gemm_mlp(
    const u16* __restrict__ Amat, const u16* __restrict__ Wt,
    const float* __restrict__ bias, const int* __restrict__ seps,
    void* __restrict__ outp) {
    constexpr int BM = 128, BN = 128, BK = 64;
    __shared__ u16 smA[BM * BK];   // 16 KB, chunked layout
    __shared__ u16 smB[BN * BK];   // 16 KB

    const int tid = threadIdx.x;
    const int wave = tid >> 6, lane = tid & 63;
    const int wm = wave >> 1, wn = wave & 1;
    const int quad = lane >> 4, l16 = lane & 15;

    const int n0 = blockIdx.x * BN;          // n fastest -> A-tile L2 reuse
    const int m0 = blockIdx.y * BM;
    const int s = seps[m0 >> 12];            // 4096 rows per agent
    const u16* Ab = Amat + (size_t)m0 * K;
    const u16* Bb = Wt + ((size_t)s * N + n0) * K;

    // staging: 16 A-chunks + 16 B-chunks per k-step, 8 insts/wave.
    // chunk c: rows g*16 + (lane&15), k = (kq0 + (lane>>4))*8 .. +7
    const int lrow = lane & 15, lkq = lane >> 4;

    floatx4 acc[4][4];
#pragma unroll
    for (int i = 0; i < 4; ++i)
#pragma unroll
        for (int j = 0; j < 4; ++j) acc[i][j] = (floatx4){0.f, 0.f, 0.f, 0.f};

    for (int k0 = 0; k0 < K; k0 += BK) {
#pragma unroll
        for (int j = 0; j < 4; ++j) {
            const int c = wave * 4 + j;
            const int row = (c >> 1) * 16 + lrow;
            const int kc = k0 + ((c & 1) * 4 + lkq) * 8;
            load16(Ab + (size_t)row * K + kc, &smA[c * 512]);
            load16(Bb + (size_t)row * K + kc, &smB[c * 512]);
        }
        __syncthreads();

#pragma unroll
        for (int h = 0; h < 2; ++h) {
            bf16x8 af[4], bfv[4];
#pragma unroll
            for (int t = 0; t < 4; ++t) {
                af[t]  = *(const bf16x8*)&smA[(wm * 4 + t) * 1024 + h * 512 + quad * 128 + l16 * 8];
                bfv[t] = *(const bf16x8*)&smB[(wn * 4 + t) * 1024 + h * 512 + quad * 128 + l16 * 8];
            }
#pragma unroll
            for (int mt = 0; mt < 4; ++mt)
#pragma unroll
                for (int nt = 0; nt < 4; ++nt)
                    acc[mt][nt] = __builtin_amdgcn_mfma_f32_16x16x32_bf16(
                        af[mt], bfv[nt], acc[mt][nt], 0, 0, 0);
        }
        __syncthreads();
    }

    // epilogue: C/D layout col=lane&15, row=quad*4+reg
#pragma unroll
    for (int nt = 0; nt < 4; ++nt) {
        const int gcol = n0 + wn * 64 + nt * 16 + l16;
        const float bv = bias[s * N + gcol];
#pragma unroll
        for (int mt = 0; mt < 4; ++mt) {
            const int grow = m0 + wm * 64 + mt * 16 + quad * 4;
#pragma unroll
            for (int r2 = 0; r2 < 4; ++r2) {
                float v = acc[mt][nt][r2] + bv;
                if (RELU) v = fmaxf(v, 0.0f);
                if (OUT_BF16)
                    ((u16*)outp)[(size_t)(grow + r2) * N + gcol] = f2bf(v);
                else
                    ((float*)outp)[(size_t)(grow + r2) * N + gcol] = v;
            }
        }
    }
}

extern "C" void kernel_launch(void* const* d_in, const int* in_sizes, int n_in,
                              void* d_out, int out_size, void* d_ws, size_t ws_size,
                              hipStream_t stream) {
    const float* x  = (const float*)d_in[0];
    const float* W1 = (const float*)d_in[1];
    const float* b1 = (const float*)d_in[2];
    const float* W2 = (const float*)d_in[3];
    const float* b2 = (const float*)d_in[4];
    const float* W3 = (const float*)d_in[5];
    const float* b3 = (const float*)d_in[6];
    const int* seps = (const int*)d_in[7];

    char* ws = (char*)d_ws;
    u16* w1t = (u16*)(ws);                    //  2 MB: [4][1024][256]
    u16* w2t = (u16*)(ws + (2ull << 20));     //  8 MB: [4][1024][1024]
    u16* w3t = (u16*)(ws + (10ull << 20));    //  4 MB: [4][512][1024]
    u16* xb  = (u16*)(ws + (14ull << 20));    // 16 MB: [32768][256]
    u16* h1  = (u16*)(ws + (30ull << 20));    // 64 MB: [32768][1024]
    u16* h2  = (u16*)(ws + (94ull << 20));    // 64 MB: [32768][1024]

    convert_f32_bf16<<<8192, 256, 0, stream>>>(x, xb, 8388608);
    transpose_to_bf16<<<dim3(32, 8, 4),  dim3(32, 8), 0, stream>>>(W1, w1t, 256, 1024);
    transpose_to_bf16<<<dim3(32, 32, 4), dim3(32, 8), 0, stream>>>(W2, w2t, 1024, 1024);
    transpose_to_bf16<<<dim3(16, 32, 4), dim3(32, 8), 0, stream>>>(W3, w3t, 1024, 512);

    // L1: [32768,256]@[256,1024]^T +b1, relu -> h1 (bf16)
    gemm_mlp<256, 1024, true, true><<<dim3(8, 256), 256, 0, stream>>>(xb, w1t, b1, seps, h1);
    // L2: [32768,1024]@[1024,1024]^T +b2, relu -> h2 (bf16)
    gemm_mlp<1024, 1024, true, true><<<dim3(8, 256), 256, 0, stream>>>(h1, w2t, b2, seps, h2);
    // L3: [32768,1024]@[1024,512]^T +b3 -> out (f32)
    gemm_mlp<1024, 512, false, false><<<dim3(4, 256), 256, 0, stream>>>(h2, w3t, b3, seps, d_out);
}

// Round 3
// 331.769 us; speedup vs baseline: 1.1427x; 1.1427x over previous
//
#include <hip/hip_runtime.h>
#include <hip/hip_bf16.h>

// MultiAgentSEPSNetwork: A=8 agents, E=4096, O=256, H1=H2=1024, H3=512, S=4.
// M = A*E = 32768 rows. Only the seps_idx-selected net per agent is computed.
//
// R3 = R1 structure (BK=32, m-fastest grid — R2's n-fastest grid + lane-scatter
// DMA regressed: FETCH 147->270MB, staging decoalesced) + XOR chunk swizzle:
// lane 4r+c fetches k-chunk c^((r>>1)&3) of row r. Same contiguous 64B row
// segment per 4-lane group (coalescing preserved); fragment ds_read_b128 now
// hits 8 distinct banks x 2 lanes per quarter-wave (2-way = free, m136)
// instead of R1's 8-way on banks {0-3,16-19}.

typedef unsigned short u16;
typedef __bf16 bf16x8 __attribute__((ext_vector_type(8)));
typedef float floatx4 __attribute__((ext_vector_type(4)));

__device__ __forceinline__ u16 f2bf(float f) {
    union { float f; unsigned int u; } v; v.f = f;
    unsigned int u = v.u;
    return (u16)((u + 0x7FFFu + ((u >> 16) & 1u)) >> 16);
}

// global -> LDS direct DMA, 16 B/lane. LDS dest = wave-uniform base + lane*16.
__device__ __forceinline__ void load16(const void* g, void* l) {
    __builtin_amdgcn_global_load_lds(
        (const __attribute__((address_space(1))) void*)(unsigned long long)g,
        (__attribute__((address_space(3))) void*)(unsigned int)(unsigned long long)l,
        16, 0, 0);
}

// ---------------- conversion kernels ----------------

__global__ void convert_f32_bf16(const float* __restrict__ src,
                                 u16* __restrict__ dst, int n) {
    int i = (blockIdx.x * blockDim.x + threadIdx.x) * 4;
    if (i < n) {
        float4 v = *(const float4*)(src + i);
        ushort4 o;
        o.x = f2bf(v.x); o.y = f2bf(v.y); o.z = f2bf(v.z); o.w = f2bf(v.w);
        *(ushort4*)(dst + i) = o;
    }
}

// [S][K][N] f32 -> [S][N][K] bf16 weight transpose (k contiguous per out row).
__global__ void transpose_to_bf16(const float* __restrict__ src,
                                  u16* __restrict__ dst, int K, int N) {
    __shared__ float tile[32][33];
    int s = blockIdx.z;
    src += (size_t)s * K * N;
    dst += (size_t)s * N * K;
    int n0 = blockIdx.x * 32, k0 = blockIdx.y * 32;
    int tx = threadIdx.x, ty = threadIdx.y;
#pragma unroll
    for (int j = 0; j < 32; j += 8)
        tile[ty + j][tx] = src[(size_t)(k0 + ty + j) * N + (n0 + tx)];
    __syncthreads();
#pragma unroll
    for (int j = 0; j < 32; j += 8)
        dst[(size_t)(n0 + ty + j) * K + (k0 + tx)] = f2bf(tile[tx][ty + j]);
}

// ---------------- grouped GEMM (m97 structure + XOR swizzle) ----------------
// C[m,n] = act(A[M,K] @ Wt[s][N,K]^T + bias[s][N]);  s = seps[agent(m)]
// 128x128 tile, BK=32, 256 thr = 4 waves (2x2), 64x64/wave, 16x16x32 MFMA.
template <int K, int N, bool RELU, bool OUT_BF16>
__global__ __launch_bounds__(256) void gemm_mlp(
    const u16* __restrict__ Amat, const u16* __restrict__ Wt,
    const float* __restrict__ bias, const int* __restrict__ seps,
    void* __restrict__ outp) {
    constexpr int BM = 128, BN = 128, BK = 32;
    __shared__ u16 smA[BM * BK];   // 8 KB; 16-row groups of 1 KB, XOR-swizzled
    __shared__ u16 smB[BN * BK];   // 8 KB

    const int tid = threadIdx.x;
    const int wave = tid >> 6, lane = tid & 63;
    const int wm = wave >> 1, wn = wave & 1;
    const int quad = lane >> 4, l16 = lane & 15;

    const int m0 = blockIdx.x * BM;            // m fastest (R1 grid: lower FETCH)
    const int n0 = blockIdx.y * BN;
    const int s = seps[m0 >> 12];              // 4096 rows per agent
    const u16* Ab = Amat + (size_t)m0 * K;
    const u16* Bb = Wt + ((size_t)s * N + n0) * K;

    // staging: lane covers row r = lane>>2 (within 16-row chunk), k-chunk
    // c' = (lane&3) ^ ((r>>1)&3)  (XOR swizzle, same 64B segment per 4 lanes)
    const int srow0 = wave * 32 + (lane >> 2);       // chunk j adds 16
    const int scol = (((lane & 3) ^ ((lane >> 3) & 3)) * 8);

    floatx4 acc[4][4];
#pragma unroll
    for (int i = 0; i < 4; ++i)
#pragma unroll
        for (int j = 0; j < 4; ++j) acc[i][j] = (floatx4){0.f, 0.f, 0.f, 0.f};

    for (int k0 = 0; k0 < K; k0 += BK) {
#pragma unroll
        for (int j = 0; j < 2; ++j) {
            const int r = srow0 + j * 16;
            load16(Ab + (size_t)r * K + k0 + scol, &smA[(wave * 2 + j) * 512]);
            load16(Bb + (size_t)r * K + k0 + scol, &smB[(wave * 2 + j) * 512]);
        }
        __syncthreads();

        // fragment read: row l16 of group, global k-chunk quad lives at slot
        // quad ^ ((l16>>1)&3)
        const int slot = (quad ^ ((l16 >> 1) & 3)) * 8;
        bf16x8 af[4], bfv[4];
#pragma unroll
        for (int t = 0; t < 4; ++t) {
            af[t]  = *(const bf16x8*)&smA[(wm * 4 + t) * 512 + l16 * 32 + slot];
            bfv[t] = *(const bf16x8*)&smB[(wn * 4 + t) * 512 + l16 * 32 + slot];
        }
#pragma unroll
        for (int mt = 0; mt < 4; ++mt)
#pragma unroll
            for (int nt = 0; nt < 4; ++nt)
                acc[mt][nt] = __builtin_amdgcn_mfma_f32_16x16x32_bf16(
                    af[mt], bfv[nt], acc[mt][nt], 0, 0, 0);
        __syncthreads();
    }

    // epilogue: C/D layout col=lane&15, row=quad*4+reg
#pragma unroll
    for (int nt = 0; nt < 4; ++nt) {
        const int gcol = n0 + wn * 64 + nt * 16 + l16;
        const float bv = bias[s * N + gcol];
#pragma unroll
        for (int mt = 0; mt < 4; ++mt) {
            const int grow = m0 + wm * 64 + mt * 16 + quad * 4;
#pragma unroll
            for (int r2 = 0; r2 < 4; ++r2) {
                float v = acc[mt][nt][r2] + bv;
                if (RELU) v = fmaxf(v, 0.0f);
                if (OUT_BF16)
                    ((u16*)outp)[(size_t)(grow + r2) * N + gcol] = f2bf(v);
                else
                    ((float*)outp)[(size_t)(grow + r2) * N + gcol] = v;
            }
        }
    }
}

extern "C" void kernel_launch(void* const* d_in, const int* in_sizes, int n_in,
                              void* d_out, int out_size, void* d_ws, size_t ws_size,
                              hipStream_t stream) {
    const float* x  = (const float*)d_in[0];
    const float* W1 = (const float*)d_in[1];
    const float* b1 = (const float*)d_in[2];
    const float* W2 = (const float*)d_in[3];
    const float* b2 = (const float*)d_in[4];
    const float* W3 = (const float*)d_in[5];
    const float* b3 = (const float*)d_in[6];
    const int* seps = (const int*)d_in[7];

    char* ws = (char*)d_ws;
    u16* w1t = (u16*)(ws);                    //  2 MB: [4][1024][256]
    u16* w2t = (u16*)(ws + (2ull << 20));     //  8 MB: [4][1024][1024]
    u16* w3t = (u16*)(ws + (10ull << 20));    //  4 MB: [4][512][1024]
    u16* xb  = (u16*)(ws + (14ull << 20));    // 16 MB: [32768][256]
    u16* h1  = (u16*)(ws + (30ull << 20));    // 64 MB: [32768][1024]
    u16* h2  = (u16*)(ws + (94ull << 20));    // 64 MB: [32768][1024]

    convert_f32_bf16<<<8192, 256, 0, stream>>>(x, xb, 8388608);
    transpose_to_bf16<<<dim3(32, 8, 4),  dim3(32, 8), 0, stream>>>(W1, w1t, 256, 1024);
    transpose_to_bf16<<<dim3(32, 32, 4), dim3(32, 8), 0, stream>>>(W2, w2t, 1024, 1024);
    transpose_to_bf16<<<dim3(16, 32, 4), dim3(32, 8), 0, stream>>>(W3, w3t, 1024, 512);

    // L1: [32768,256]@[256,1024]^T +b1, relu -> h1 (bf16)
    gemm_mlp<256, 1024, true, true><<<dim3(256, 8), 256, 0, stream>>>(xb, w1t, b1, seps, h1);
    // L2: [32768,1024]@[1024,1024]^T +b2, relu -> h2 (bf16)
    gemm_mlp<1024, 1024, true, true><<<dim3(256, 8), 256, 0, stream>>>(h1, w2t, b2, seps, h2);
    // L3: [32768,1024]@[1024,512]^T +b3 -> out (f32)
    gemm_mlp<1024, 512, false, false><<<dim3(256, 4), 256, 0, stream>>>(h2, w3t, b3, seps, d_out);
}

// Round 4
// 309.607 us; speedup vs baseline: 1.2245x; 1.0716x over previous
//
#include <hip/hip_runtime.h>
#include <hip/hip_bf16.h>

// MultiAgentSEPSNetwork: A=8 agents, E=4096, O=256, H1=H2=1024, H3=512, S=4.
// M = A*E = 32768 rows. Only the seps_idx-selected net per agent is computed.
//
// R4 vs R3 (L2 GEMM 117us, MfmaUtil 24%, conflicts 0 but neutral -> stalls are
// barrier+epilogue, not LDS):
//  - BK=64: half the barriers (32 MFMA per sync). LDS rows are 128B row-major
//    with XOR-8 slot swizzle; staging 8-lane groups stay on one contiguous
//    128B global row segment (R2's decoalescing avoided), fragment reads are
//    2-way bank aliased (free, m136).
//  - Epilogue: LDS-transpose in 4 phases -> 16B/lane coalesced stores
//    (replaces 64 scalar 2B stores/thread, ~E=3600cyc/block per R3 model).

typedef unsigned short u16;
typedef __bf16 bf16x8 __attribute__((ext_vector_type(8)));
typedef float floatx4 __attribute__((ext_vector_type(4)));
typedef unsigned short ushort8 __attribute__((ext_vector_type(8)));

__device__ __forceinline__ u16 f2bf(float f) {
    union { float f; unsigned int u; } v; v.f = f;
    unsigned int u = v.u;
    return (u16)((u + 0x7FFFu + ((u >> 16) & 1u)) >> 16);
}

// global -> LDS direct DMA, 16 B/lane. LDS dest = wave-uniform base + lane*16.
__device__ __forceinline__ void load16(const void* g, void* l) {
    __builtin_amdgcn_global_load_lds(
        (const __attribute__((address_space(1))) void*)(unsigned long long)g,
        (__attribute__((address_space(3))) void*)(unsigned int)(unsigned long long)l,
        16, 0, 0);
}

// ---------------- conversion kernels ----------------

__global__ void convert_f32_bf16(const float* __restrict__ src,
                                 u16* __restrict__ dst, int n) {
    int i = (blockIdx.x * blockDim.x + threadIdx.x) * 4;
    if (i < n) {
        float4 v = *(const float4*)(src + i);
        ushort4 o;
        o.x = f2bf(v.x); o.y = f2bf(v.y); o.z = f2bf(v.z); o.w = f2bf(v.w);
        *(ushort4*)(dst + i) = o;
    }
}

// [S][K][N] f32 -> [S][N][K] bf16 weight transpose (k contiguous per out row).
__global__ void transpose_to_bf16(const float* __restrict__ src,
                                  u16* __restrict__ dst, int K, int N) {
    __shared__ float tile[32][33];
    int s = blockIdx.z;
    src += (size_t)s * K * N;
    dst += (size_t)s * N * K;
    int n0 = blockIdx.x * 32, k0 = blockIdx.y * 32;
    int tx = threadIdx.x, ty = threadIdx.y;
#pragma unroll
    for (int j = 0; j < 32; j += 8)
        tile[ty + j][tx] = src[(size_t)(k0 + ty + j) * N + (n0 + tx)];
    __syncthreads();
#pragma unroll
    for (int j = 0; j < 32; j += 8)
        dst[(size_t)(n0 + ty + j) * K + (k0 + tx)] = f2bf(tile[tx][ty + j]);
}

// ---------------- grouped GEMM, BK=64 + coalesced epilogue ----------------
// C[m,n] = act(A[M,K] @ Wt[s][N,K]^T + bias[s][N]);  s = seps[agent(m)]
// 128x128 tile, BK=64, 256 thr = 4 waves (2x2), 64x64/wave, 16x16x32 MFMA.
//
// LDS A/B tiles: [row][slot] where slot q of row r holds global k-chunk
// q^(r&7) (8 bf16 per chunk). Rows are 128 B; staging chunk c = 8 rows,
// lane L -> row c*8+(L>>3), global k-chunk (L&7)^(L>>3) -> same contiguous
// 128 B row segment per 8 lanes.
template <int K, int N, bool RELU, bool OUT_BF16>
__global__ __launch_bounds__(256) void gemm_mlp(
    const u16* __restrict__ Amat, const u16* __restrict__ Wt,
    const float* __restrict__ bias, const int* __restrict__ seps,
    void* __restrict__ outp) {
    constexpr int BM = 128, BN = 128, BK = 64;
    constexpr int EW = 132;                    // epilogue f32 row stride
    __shared__ float4 ldsbuf[2048];            // 32 KB
    u16* smA = (u16*)ldsbuf;                   // 16 KB
    u16* smB = (u16*)ldsbuf + 8192;            // 16 KB
    float* eps = (float*)ldsbuf;               // 32x132 f32 = 16.5 KB (epilogue)

    const int tid = threadIdx.x;
    const int wave = tid >> 6, lane = tid & 63;
    const int wm = wave >> 1, wn = wave & 1;
    const int quad = lane >> 4, l16 = lane & 15;

    const int m0 = blockIdx.x * BM;            // m fastest (B-tile L2 reuse)
    const int n0 = blockIdx.y * BN;
    const int s = seps[m0 >> 12];              // 4096 rows per agent
    const u16* Ab = Amat + (size_t)m0 * K;
    const u16* Bb = Wt + ((size_t)s * N + n0) * K;

    // staging lane coords (within an 8-row chunk)
    const int srow = lane >> 3;                          // 0..7
    const int sk = ((lane & 7) ^ (lane >> 3)) * 8;       // swizzled k-chunk, u16 units

    floatx4 acc[4][4];
#pragma unroll
    for (int i = 0; i < 4; ++i)
#pragma unroll
        for (int j = 0; j < 4; ++j) acc[i][j] = (floatx4){0.f, 0.f, 0.f, 0.f};

    for (int k0 = 0; k0 < K; k0 += BK) {
#pragma unroll
        for (int j = 0; j < 4; ++j) {
            const int c = wave * 4 + j;                  // chunk 0..15
            const int row = c * 8 + srow;
            load16(Ab + (size_t)row * K + k0 + sk, &smA[c * 512]);
            load16(Bb + (size_t)row * K + k0 + sk, &smB[c * 512]);
        }
        __syncthreads();

#pragma unroll
        for (int h = 0; h < 2; ++h) {
            const int slot = ((h * 4 + quad) ^ (l16 & 7)) * 8;
            bf16x8 af[4], bfv[4];
#pragma unroll
            for (int t = 0; t < 4; ++t) {
                af[t]  = *(const bf16x8*)&smA[(wm * 64 + t * 16 + l16) * 64 + slot];
                bfv[t] = *(const bf16x8*)&smB[(wn * 64 + t * 16 + l16) * 64 + slot];
            }
#pragma unroll
            for (int mt = 0; mt < 4; ++mt)
#pragma unroll
                for (int nt = 0; nt < 4; ++nt)
                    acc[mt][nt] = __builtin_amdgcn_mfma_f32_16x16x32_bf16(
                        af[mt], bfv[nt], acc[mt][nt], 0, 0, 0);
        }
        __syncthreads();
    }

    // ---- epilogue: 4 phases, LDS transpose, 16B/lane coalesced stores ----
    float bv[4];
#pragma unroll
    for (int nt = 0; nt < 4; ++nt)
        bv[nt] = bias[s * N + n0 + wn * 64 + nt * 16 + l16];

    const int rr = tid >> 4;      // 0..15 (readback row within half-region)
    const int cg = tid & 15;      // 0..15 (8 cols each -> 128 cols)

#pragma unroll
    for (int mt = 0; mt < 4; ++mt) {
        // write: C/D layout col=l16, row=quad*4+r2
#pragma unroll
        for (int nt = 0; nt < 4; ++nt) {
#pragma unroll
            for (int r2 = 0; r2 < 4; ++r2) {
                float v = acc[mt][nt][r2] + bv[nt];
                if (RELU) v = fmaxf(v, 0.0f);
                eps[(wm * 16 + quad * 4 + r2) * EW + wn * 64 + nt * 16 + l16] = v;
            }
        }
        __syncthreads();
        // read row-major + store coalesced
#pragma unroll
        for (int p = 0; p < 2; ++p) {
            const int lrow = p * 16 + rr;  // 0..31
            const int grow = m0 + ((lrow < 16) ? (mt * 16 + lrow)
                                               : (64 + mt * 16 + (lrow - 16)));
            const float* src = eps + lrow * EW + cg * 8;
            float4 v0 = *(const float4*)(src);
            float4 v1 = *(const float4*)(src + 4);
            if (OUT_BF16) {
                ushort8 o;
                o[0] = f2bf(v0.x); o[1] = f2bf(v0.y); o[2] = f2bf(v0.z); o[3] = f2bf(v0.w);
                o[4] = f2bf(v1.x); o[5] = f2bf(v1.y); o[6] = f2bf(v1.z); o[7] = f2bf(v1.w);
                *(ushort8*)((u16*)outp + (size_t)grow * N + n0 + cg * 8) = o;
            } else {
                float* dst = (float*)outp + (size_t)grow * N + n0 + cg * 8;
                *(float4*)dst = v0;
                *(float4*)(dst + 4) = v1;
            }
        }
        __syncthreads();
    }
}

extern "C" void kernel_launch(void* const* d_in, const int* in_sizes, int n_in,
                              void* d_out, int out_size, void* d_ws, size_t ws_size,
                              hipStream_t stream) {
    const float* x  = (const float*)d_in[0];
    const float* W1 = (const float*)d_in[1];
    const float* b1 = (const float*)d_in[2];
    const float* W2 = (const float*)d_in[3];
    const float* b2 = (const float*)d_in[4];
    const float* W3 = (const float*)d_in[5];
    const float* b3 = (const float*)d_in[6];
    const int* seps = (const int*)d_in[7];

    char* ws = (char*)d_ws;
    u16* w1t = (u16*)(ws);                    //  2 MB: [4][1024][256]
    u16* w2t = (u16*)(ws + (2ull << 20));     //  8 MB: [4][1024][1024]
    u16* w3t = (u16*)(ws + (10ull << 20));    //  4 MB: [4][512][1024]
    u16* xb  = (u16*)(ws + (14ull << 20));    // 16 MB: [32768][256]
    u16* h1  = (u16*)(ws + (30ull << 20));    // 64 MB: [32768][1024]
    u16* h2  = (u16*)(ws + (94ull << 20));    // 64 MB: [32768][1024]

    convert_f32_bf16<<<8192, 256, 0, stream>>>(x, xb, 8388608);
    transpose_to_bf16<<<dim3(32, 8, 4),  dim3(32, 8), 0, stream>>>(W1, w1t, 256, 1024);
    transpose_to_bf16<<<dim3(32, 32, 4), dim3(32, 8), 0, stream>>>(W2, w2t, 1024, 1024);
    transpose_to_bf16<<<dim3(16, 32, 4), dim3(32, 8), 0, stream>>>(W3, w3t, 1024, 512);

    // L1: [32768,256]@[256,1024]^T +b1, relu -> h1 (bf16)
    gemm_mlp<256, 1024, true, true><<<dim3(256, 8), 256, 0, stream>>>(xb, w1t, b1, seps, h1);
    // L2: [32768,1024]@[1024,1024]^T +b2, relu -> h2 (bf16)
    gemm_mlp<1024, 1024, true, true><<<dim3(256, 8), 256, 0, stream>>>(h1, w2t, b2, seps, h2);
    // L3: [32768,1024]@[1024,512]^T +b3 -> out (f32)
    gemm_mlp<1024, 512, false, false><<<dim3(256, 4), 256, 0, stream>>>(h2, w3t, b3, seps, d_out);
}

// Round 5
// 307.432 us; speedup vs baseline: 1.2331x; 1.0071x over previous
//
#include <hip/hip_runtime.h>
#include <hip/hip_bf16.h>

// MultiAgentSEPSNetwork: A=8 agents, E=4096, O=256, H1=H2=1024, H3=512, S=4.
// M = A*E = 32768 rows. Only the seps_idx-selected net per agent is computed.
//
// R5 vs R4 (L2 GEMM 101us, MfmaUtil 28%, FETCH 196MB; K-loop latency-pinned
// on A-staging that misses L2 because same-A blocks land on different XCDs):
//  - XCD-aware block swizzle: HW maps block i -> XCD i%8. We encode
//    i = ((mg*NNB + nb)<<3) | (m%8) so all NNB n-blocks of an m-stripe are
//    dispatch-adjacent AND on one XCD -> A-tile fetched to that L2 once,
//    hit NNB-1 times; A-staging latency ~600 -> ~200cyc.
//  - prep (x-convert + 3 weight transposes) merged into ONE kernel (fewer
//    launch/drain boundaries).
// Kept from R4: BK=64, XOR-swizzled LDS (0 bank conflicts), global_load_lds
// width=16 with segment-contiguous lane order, coalesced LDS-transpose
// epilogue.

typedef unsigned short u16;
typedef __bf16 bf16x8 __attribute__((ext_vector_type(8)));
typedef float floatx4 __attribute__((ext_vector_type(4)));
typedef unsigned short ushort8 __attribute__((ext_vector_type(8)));

__device__ __forceinline__ u16 f2bf(float f) {
    union { float f; unsigned int u; } v; v.f = f;
    unsigned int u = v.u;
    return (u16)((u + 0x7FFFu + ((u >> 16) & 1u)) >> 16);
}

// global -> LDS direct DMA, 16 B/lane. LDS dest = wave-uniform base + lane*16.
__device__ __forceinline__ void load16(const void* g, void* l) {
    __builtin_amdgcn_global_load_lds(
        (const __attribute__((address_space(1))) void*)(unsigned long long)g,
        (__attribute__((address_space(3))) void*)(unsigned int)(unsigned long long)l,
        16, 0, 0);
}

// ---------------- fused prep: x->bf16 + 3 weight transposes ----------------
// blocks [0,8192): convert x (4 f32/thread)
// blocks [8192,9216):  W1 [4][256][1024]  -> [4][1024][256]
// blocks [9216,13312): W2 [4][1024][1024] -> [4][1024][1024]
// blocks [13312,15360): W3 [4][1024][512] -> [4][512][1024]
__global__ __launch_bounds__(256) void prep(
    const float* __restrict__ x, u16* __restrict__ xb,
    const float* __restrict__ W1, u16* __restrict__ w1t,
    const float* __restrict__ W2, u16* __restrict__ w2t,
    const float* __restrict__ W3, u16* __restrict__ w3t) {
    __shared__ float tile[32][33];
    int b = blockIdx.x;
    const int tid = threadIdx.x;
    if (b < 8192) {
        int i = (b * 256 + tid) * 4;
        float4 v = *(const float4*)(x + i);
        ushort4 o;
        o.x = f2bf(v.x); o.y = f2bf(v.y); o.z = f2bf(v.z); o.w = f2bf(v.w);
        *(ushort4*)(xb + i) = o;
        return;
    }
    b -= 8192;
    const float* src; u16* dst; int K, N, n0, k0, s;
    if (b < 1024) {                     // W1: 256 tiles per s
        s = b >> 8; int r = b & 255;
        K = 256; N = 1024; n0 = (r & 31) * 32; k0 = (r >> 5) * 32;
        src = W1; dst = w1t;
    } else if (b < 5120) {              // W2: 1024 tiles per s
        b -= 1024; s = b >> 10; int r = b & 1023;
        K = 1024; N = 1024; n0 = (r & 31) * 32; k0 = (r >> 5) * 32;
        src = W2; dst = w2t;
    } else {                            // W3: 512 tiles per s
        b -= 5120; s = b >> 9; int r = b & 511;
        K = 1024; N = 512; n0 = (r & 15) * 32; k0 = (r >> 4) * 32;
        src = W3; dst = w3t;
    }
    src += (size_t)s * K * N;
    dst += (size_t)s * N * K;
    const int tx = tid & 31, ty = tid >> 5;
#pragma unroll
    for (int j = 0; j < 32; j += 8)
        tile[ty + j][tx] = src[(size_t)(k0 + ty + j) * N + (n0 + tx)];
    __syncthreads();
#pragma unroll
    for (int j = 0; j < 32; j += 8)
        dst[(size_t)(n0 + ty + j) * K + (k0 + tx)] = f2bf(tile[tx][ty + j]);
}

// ---------------- grouped GEMM, XCD-swizzled grid ----------------
// C[m,n] = act(A[M,K] @ Wt[s][N,K]^T + bias[s][N]);  s = seps[agent(m)]
// 128x128 tile, BK=64, 256 thr = 4 waves (2x2), 64x64/wave, 16x16x32 MFMA.
template <int K, int N, bool RELU, bool OUT_BF16>
__global__ __launch_bounds__(256) void gemm_mlp(
    const u16* __restrict__ Amat, const u16* __restrict__ Wt,
    const float* __restrict__ bias, const int* __restrict__ seps,
    void* __restrict__ outp) {
    constexpr int BM = 128, BN = 128, BK = 64;
    constexpr int NNB = N / 128;               // n-blocks per m-stripe (8 or 4)
    constexpr int LNB = (NNB == 8) ? 3 : 2;
    constexpr int EW = 132;                    // epilogue f32 row stride
    __shared__ float4 ldsbuf[2048];            // 32 KB
    u16* smA = (u16*)ldsbuf;                   // 16 KB
    u16* smB = (u16*)ldsbuf + 8192;            // 16 KB
    float* eps = (float*)ldsbuf;               // 32x132 f32 (epilogue reuse)

    const int tid = threadIdx.x;
    const int wave = tid >> 6, lane = tid & 63;
    const int wm = wave >> 1, wn = wave & 1;
    const int quad = lane >> 4, l16 = lane & 15;

    // XCD swizzle: block i -> XCD i%8. All NNB n-blocks of one m-stripe are
    // adjacent in dispatch order and share i%8 == m%8 -> same XCD L2 holds
    // the A-tile for all of them.
    const int bidx = blockIdx.x;
    const int t = bidx >> 3;
    const int mb = (t >> LNB) * 8 + (bidx & 7);
    const int nb = t & (NNB - 1);
    const int m0 = mb * BM;
    const int n0 = nb * BN;

    const int s = seps[m0 >> 12];              // 4096 rows per agent
    const u16* Ab = Amat + (size_t)m0 * K;
    const u16* Bb = Wt + ((size_t)s * N + n0) * K;

    // staging lane coords: chunk = 8 rows; lane L -> row c*8+(L>>3),
    // k-chunk (L&7)^(L>>3) -> same contiguous 128B row segment per 8 lanes.
    const int srow = lane >> 3;
    const int sk = ((lane & 7) ^ (lane >> 3)) * 8;

    floatx4 acc[4][4];
#pragma unroll
    for (int i = 0; i < 4; ++i)
#pragma unroll
        for (int j = 0; j < 4; ++j) acc[i][j] = (floatx4){0.f, 0.f, 0.f, 0.f};

    for (int k0 = 0; k0 < K; k0 += BK) {
#pragma unroll
        for (int j = 0; j < 4; ++j) {
            const int c = wave * 4 + j;                  // chunk 0..15
            const int row = c * 8 + srow;
            load16(Ab + (size_t)row * K + k0 + sk, &smA[c * 512]);
            load16(Bb + (size_t)row * K + k0 + sk, &smB[c * 512]);
        }
        __syncthreads();

#pragma unroll
        for (int h = 0; h < 2; ++h) {
            const int slot = ((h * 4 + quad) ^ (l16 & 7)) * 8;
            bf16x8 af[4], bfv[4];
#pragma unroll
            for (int t2 = 0; t2 < 4; ++t2) {
                af[t2]  = *(const bf16x8*)&smA[(wm * 64 + t2 * 16 + l16) * 64 + slot];
                bfv[t2] = *(const bf16x8*)&smB[(wn * 64 + t2 * 16 + l16) * 64 + slot];
            }
#pragma unroll
            for (int mt = 0; mt < 4; ++mt)
#pragma unroll
                for (int nt = 0; nt < 4; ++nt)
                    acc[mt][nt] = __builtin_amdgcn_mfma_f32_16x16x32_bf16(
                        af[mt], bfv[nt], acc[mt][nt], 0, 0, 0);
        }
        __syncthreads();
    }

    // ---- epilogue: 4 phases, LDS transpose, 16B/lane coalesced stores ----
    float bv[4];
#pragma unroll
    for (int nt = 0; nt < 4; ++nt)
        bv[nt] = bias[s * N + n0 + wn * 64 + nt * 16 + l16];

    const int rr = tid >> 4;      // 0..15
    const int cg = tid & 15;      // 0..15 (8 cols each)

#pragma unroll
    for (int mt = 0; mt < 4; ++mt) {
#pragma unroll
        for (int nt = 0; nt < 4; ++nt) {
#pragma unroll
            for (int r2 = 0; r2 < 4; ++r2) {
                float v = acc[mt][nt][r2] + bv[nt];
                if (RELU) v = fmaxf(v, 0.0f);
                eps[(wm * 16 + quad * 4 + r2) * EW + wn * 64 + nt * 16 + l16] = v;
            }
        }
        __syncthreads();
#pragma unroll
        for (int p = 0; p < 2; ++p) {
            const int lrow = p * 16 + rr;  // 0..31
            const int grow = m0 + ((lrow < 16) ? (mt * 16 + lrow)
                                               : (64 + mt * 16 + (lrow - 16)));
            const float* src = eps + lrow * EW + cg * 8;
            float4 v0 = *(const float4*)(src);
            float4 v1 = *(const float4*)(src + 4);
            if (OUT_BF16) {
                ushort8 o;
                o[0] = f2bf(v0.x); o[1] = f2bf(v0.y); o[2] = f2bf(v0.z); o[3] = f2bf(v0.w);
                o[4] = f2bf(v1.x); o[5] = f2bf(v1.y); o[6] = f2bf(v1.z); o[7] = f2bf(v1.w);
                *(ushort8*)((u16*)outp + (size_t)grow * N + n0 + cg * 8) = o;
            } else {
                float* dst = (float*)outp + (size_t)grow * N + n0 + cg * 8;
                *(float4*)dst = v0;
                *(float4*)(dst + 4) = v1;
            }
        }
        __syncthreads();
    }
}

extern "C" void kernel_launch(void* const* d_in, const int* in_sizes, int n_in,
                              void* d_out, int out_size, void* d_ws, size_t ws_size,
                              hipStream_t stream) {
    const float* x  = (const float*)d_in[0];
    const float* W1 = (const float*)d_in[1];
    const float* b1 = (const float*)d_in[2];
    const float* W2 = (const float*)d_in[3];
    const float* b2 = (const float*)d_in[4];
    const float* W3 = (const float*)d_in[5];
    const float* b3 = (const float*)d_in[6];
    const int* seps = (const int*)d_in[7];

    char* ws = (char*)d_ws;
    u16* w1t = (u16*)(ws);                    //  2 MB: [4][1024][256]
    u16* w2t = (u16*)(ws + (2ull << 20));     //  8 MB: [4][1024][1024]
    u16* w3t = (u16*)(ws + (10ull << 20));    //  4 MB: [4][512][1024]
    u16* xb  = (u16*)(ws + (14ull << 20));    // 16 MB: [32768][256]
    u16* h1  = (u16*)(ws + (30ull << 20));    // 64 MB: [32768][1024]
    u16* h2  = (u16*)(ws + (94ull << 20));    // 64 MB: [32768][1024]

    prep<<<15360, 256, 0, stream>>>(x, xb, W1, w1t, W2, w2t, W3, w3t);

    // L1: [32768,256]@[256,1024]^T +b1, relu -> h1 (bf16)
    gemm_mlp<256, 1024, true, true><<<2048, 256, 0, stream>>>(xb, w1t, b1, seps, h1);
    // L2: [32768,1024]@[1024,1024]^T +b2, relu -> h2 (bf16)
    gemm_mlp<1024, 1024, true, true><<<2048, 256, 0, stream>>>(h1, w2t, b2, seps, h2);
    // L3: [32768,1024]@[1024,512]^T +b3 -> out (f32)
    gemm_mlp<1024, 512, false, false><<<1024, 256, 0, stream>>>(h2, w3t, b3, seps, d_out);
}

// Round 6
// 290.893 us; speedup vs baseline: 1.3032x; 1.0569x over previous
//
#include <hip/hip_runtime.h>
#include <hip/hip_bf16.h>

// MultiAgentSEPSNetwork: A=8 agents, E=4096, O=256, H1=H2=1024, H3=512, S=4.
// M = A*E = 32768 rows. Only the seps_idx-selected net per agent is computed.
//
// R6 vs R5 (L2 GEMM 107us, MfmaUtil 26.5%; per-iter wall ~2000cyc vs 515cyc
// MFMA -> ~1200cyc exposed vmcnt drain at each barrier):
//  - DOUBLE-BUFFERED K-loop, ONE barrier per iter: barrier drains the loads
//    issued during the PREVIOUS compute phase (latency hidden under ~700cyc
//    of MFMA), then next-tile loads are issued, then compute. 64 KB LDS ->
//    2 blocks/CU (LDS-capped) vs measured ~1.7-2 effective residency: no loss.
//  - XCD swizzle REVERTED (R5: FETCH halved as predicted but time +6% —
//    same-A blocks ran in parallel on 8 XCDs in natural order; serializing
//    them for L2 hits bought nothing). Grid = R4 m-fastest.
// Kept: BK=64, XOR-swizzled LDS (0 conflicts), global_load_lds width=16
// segment-contiguous staging, fused prep, coalesced LDS-transpose epilogue.

typedef unsigned short u16;
typedef __bf16 bf16x8 __attribute__((ext_vector_type(8)));
typedef float floatx4 __attribute__((ext_vector_type(4)));
typedef unsigned short ushort8 __attribute__((ext_vector_type(8)));

__device__ __forceinline__ u16 f2bf(float f) {
    union { float f; unsigned int u; } v; v.f = f;
    unsigned int u = v.u;
    return (u16)((u + 0x7FFFu + ((u >> 16) & 1u)) >> 16);
}

// global -> LDS direct DMA, 16 B/lane. LDS dest = wave-uniform base + lane*16.
__device__ __forceinline__ void load16(const void* g, void* l) {
    __builtin_amdgcn_global_load_lds(
        (const __attribute__((address_space(1))) void*)(unsigned long long)g,
        (__attribute__((address_space(3))) void*)(unsigned int)(unsigned long long)l,
        16, 0, 0);
}

// ---------------- fused prep: x->bf16 + 3 weight transposes ----------------
__global__ __launch_bounds__(256) void prep(
    const float* __restrict__ x, u16* __restrict__ xb,
    const float* __restrict__ W1, u16* __restrict__ w1t,
    const float* __restrict__ W2, u16* __restrict__ w2t,
    const float* __restrict__ W3, u16* __restrict__ w3t) {
    __shared__ float tile[32][33];
    int b = blockIdx.x;
    const int tid = threadIdx.x;
    if (b < 8192) {
        int i = (b * 256 + tid) * 4;
        float4 v = *(const float4*)(x + i);
        ushort4 o;
        o.x = f2bf(v.x); o.y = f2bf(v.y); o.z = f2bf(v.z); o.w = f2bf(v.w);
        *(ushort4*)(xb + i) = o;
        return;
    }
    b -= 8192;
    const float* src; u16* dst; int K, N, n0, k0, s;
    if (b < 1024) {                     // W1 [4][256][1024] -> [4][1024][256]
        s = b >> 8; int r = b & 255;
        K = 256; N = 1024; n0 = (r & 31) * 32; k0 = (r >> 5) * 32;
        src = W1; dst = w1t;
    } else if (b < 5120) {              // W2 [4][1024][1024] -> same^T
        b -= 1024; s = b >> 10; int r = b & 1023;
        K = 1024; N = 1024; n0 = (r & 31) * 32; k0 = (r >> 5) * 32;
        src = W2; dst = w2t;
    } else {                            // W3 [4][1024][512] -> [4][512][1024]
        b -= 5120; s = b >> 9; int r = b & 511;
        K = 1024; N = 512; n0 = (r & 15) * 32; k0 = (r >> 4) * 32;
        src = W3; dst = w3t;
    }
    src += (size_t)s * K * N;
    dst += (size_t)s * N * K;
    const int tx = tid & 31, ty = tid >> 5;
#pragma unroll
    for (int j = 0; j < 32; j += 8)
        tile[ty + j][tx] = src[(size_t)(k0 + ty + j) * N + (n0 + tx)];
    __syncthreads();
#pragma unroll
    for (int j = 0; j < 32; j += 8)
        dst[(size_t)(n0 + ty + j) * K + (k0 + tx)] = f2bf(tile[tx][ty + j]);
}

// ---------------- grouped GEMM, double-buffered K-loop ----------------
// C[m,n] = act(A[M,K] @ Wt[s][N,K]^T + bias[s][N]);  s = seps[agent(m)]
// 128x128 tile, BK=64 x2 buffers, 256 thr = 4 waves (2x2), 16x16x32 MFMA.
template <int K, int N, bool RELU, bool OUT_BF16>
__global__ __launch_bounds__(256) void gemm_mlp(
    const u16* __restrict__ Amat, const u16* __restrict__ Wt,
    const float* __restrict__ bias, const int* __restrict__ seps,
    void* __restrict__ outp) {
    constexpr int BM = 128, BN = 128, BK = 64;
    constexpr int NIT = K / BK;
    constexpr int EW = 132;                    // epilogue f32 row stride
    __shared__ u16 lds[4 * 8192];              // 64 KB: buf b at b*16384; A then B
    float* eps = (float*)lds;                  // 32x132 f32 (epilogue reuse)

    const int tid = threadIdx.x;
    const int wave = tid >> 6, lane = tid & 63;
    const int wm = wave >> 1, wn = wave & 1;
    const int quad = lane >> 4, l16 = lane & 15;

    const int m0 = blockIdx.x * BM;            // m fastest (R4 grid)
    const int n0 = blockIdx.y * BN;
    const int s = seps[m0 >> 12];              // 4096 rows per agent
    const u16* Ab = Amat + (size_t)m0 * K;
    const u16* Bb = Wt + ((size_t)s * N + n0) * K;

    // staging: chunk = 8 rows; lane L -> row c*8+(L>>3), k-chunk (L&7)^(L>>3)
    // -> same contiguous 128B global row segment per 8 lanes (coalesced).
    const int srow = lane >> 3;
    const int sk = ((lane & 7) ^ (lane >> 3)) * 8;

    floatx4 acc[4][4];
#pragma unroll
    for (int i = 0; i < 4; ++i)
#pragma unroll
        for (int j = 0; j < 4; ++j) acc[i][j] = (floatx4){0.f, 0.f, 0.f, 0.f};

    // prologue: stage tile 0 into buf 0
#pragma unroll
    for (int j = 0; j < 4; ++j) {
        const int c = wave * 4 + j;
        const int row = c * 8 + srow;
        load16(Ab + (size_t)row * K + sk, &lds[c * 512]);
        load16(Bb + (size_t)row * K + sk, &lds[8192 + c * 512]);
    }

    for (int it = 0; it < NIT; ++it) {
        __syncthreads();   // drains loads into buf it&1 (hidden under prev compute)
        if (it + 1 < NIT) {
            const int k0 = (it + 1) * BK;
            u16* dstb = &lds[((it + 1) & 1) * 16384];
#pragma unroll
            for (int j = 0; j < 4; ++j) {
                const int c = wave * 4 + j;
                const int row = c * 8 + srow;
                load16(Ab + (size_t)row * K + k0 + sk, dstb + c * 512);
                load16(Bb + (size_t)row * K + k0 + sk, dstb + 8192 + c * 512);
            }
        }
        const u16* smA = &lds[(it & 1) * 16384];
        const u16* smB = smA + 8192;
#pragma unroll
        for (int h = 0; h < 2; ++h) {
            const int slot = ((h * 4 + quad) ^ (l16 & 7)) * 8;
            bf16x8 af[4], bfv[4];
#pragma unroll
            for (int t2 = 0; t2 < 4; ++t2) {
                af[t2]  = *(const bf16x8*)&smA[(wm * 64 + t2 * 16 + l16) * 64 + slot];
                bfv[t2] = *(const bf16x8*)&smB[(wn * 64 + t2 * 16 + l16) * 64 + slot];
            }
#pragma unroll
            for (int mt = 0; mt < 4; ++mt)
#pragma unroll
                for (int nt = 0; nt < 4; ++nt)
                    acc[mt][nt] = __builtin_amdgcn_mfma_f32_16x16x32_bf16(
                        af[mt], bfv[nt], acc[mt][nt], 0, 0, 0);
        }
    }
    __syncthreads();   // all waves done with LDS tiles before epilogue reuse

    // ---- epilogue: 4 phases, LDS transpose, 16B/lane coalesced stores ----
    float bv[4];
#pragma unroll
    for (int nt = 0; nt < 4; ++nt)
        bv[nt] = bias[s * N + n0 + wn * 64 + nt * 16 + l16];

    const int rr = tid >> 4;      // 0..15
    const int cg = tid & 15;      // 0..15 (8 cols each)

#pragma unroll
    for (int mt = 0; mt < 4; ++mt) {
#pragma unroll
        for (int nt = 0; nt < 4; ++nt) {
#pragma unroll
            for (int r2 = 0; r2 < 4; ++r2) {
                float v = acc[mt][nt][r2] + bv[nt];
                if (RELU) v = fmaxf(v, 0.0f);
                eps[(wm * 16 + quad * 4 + r2) * EW + wn * 64 + nt * 16 + l16] = v;
            }
        }
        __syncthreads();
#pragma unroll
        for (int p = 0; p < 2; ++p) {
            const int lrow = p * 16 + rr;  // 0..31
            const int grow = m0 + ((lrow < 16) ? (mt * 16 + lrow)
                                               : (64 + mt * 16 + (lrow - 16)));
            const float* src = eps + lrow * EW + cg * 8;
            float4 v0 = *(const float4*)(src);
            float4 v1 = *(const float4*)(src + 4);
            if (OUT_BF16) {
                ushort8 o;
                o[0] = f2bf(v0.x); o[1] = f2bf(v0.y); o[2] = f2bf(v0.z); o[3] = f2bf(v0.w);
                o[4] = f2bf(v1.x); o[5] = f2bf(v1.y); o[6] = f2bf(v1.z); o[7] = f2bf(v1.w);
                *(ushort8*)((u16*)outp + (size_t)grow * N + n0 + cg * 8) = o;
            } else {
                float* dst = (float*)outp + (size_t)grow * N + n0 + cg * 8;
                *(float4*)dst = v0;
                *(float4*)(dst + 4) = v1;
            }
        }
        __syncthreads();
    }
}

extern "C" void kernel_launch(void* const* d_in, const int* in_sizes, int n_in,
                              void* d_out, int out_size, void* d_ws, size_t ws_size,
                              hipStream_t stream) {
    const float* x  = (const float*)d_in[0];
    const float* W1 = (const float*)d_in[1];
    const float* b1 = (const float*)d_in[2];
    const float* W2 = (const float*)d_in[3];
    const float* b2 = (const float*)d_in[4];
    const float* W3 = (const float*)d_in[5];
    const float* b3 = (const float*)d_in[6];
    const int* seps = (const int*)d_in[7];

    char* ws = (char*)d_ws;
    u16* w1t = (u16*)(ws);                    //  2 MB: [4][1024][256]
    u16* w2t = (u16*)(ws + (2ull << 20));     //  8 MB: [4][1024][1024]
    u16* w3t = (u16*)(ws + (10ull << 20));    //  4 MB: [4][512][1024]
    u16* xb  = (u16*)(ws + (14ull << 20));    // 16 MB: [32768][256]
    u16* h1  = (u16*)(ws + (30ull << 20));    // 64 MB: [32768][1024]
    u16* h2  = (u16*)(ws + (94ull << 20));    // 64 MB: [32768][1024]

    prep<<<15360, 256, 0, stream>>>(x, xb, W1, w1t, W2, w2t, W3, w3t);

    // L1: [32768,256]@[256,1024]^T +b1, relu -> h1 (bf16)
    gemm_mlp<256, 1024, true, true><<<dim3(256, 8), 256, 0, stream>>>(xb, w1t, b1, seps, h1);
    // L2: [32768,1024]@[1024,1024]^T +b2, relu -> h2 (bf16)
    gemm_mlp<1024, 1024, true, true><<<dim3(256, 8), 256, 0, stream>>>(h1, w2t, b2, seps, h2);
    // L3: [32768,1024]@[1024,512]^T +b3 -> out (f32)
    gemm_mlp<1024, 512, false, false><<<dim3(256, 4), 256, 0, stream>>>(h2, w3t, b3, seps, d_out);
}

// Round 8
// 272.766 us; speedup vs baseline: 1.3898x; 1.0665x over previous
//
#include <hip/hip_runtime.h>
#include <hip/hip_bf16.h>

// MultiAgentSEPSNetwork: A=8 agents, E=4096, O=256, H1=H2=1024, H3=512, S=4.
// M = A*E = 32768 rows. Only the seps_idx-selected net per agent is computed.
//
// R8 = R7 resubmitted verbatim (R7 bench failed with GPUAcquisitionTimeout —
// infra, no data). R6 dbuf K-loop + R5 XCD swizzle:
// R6 post-mortem: with the vmcnt drain pipelined away, L2 GEMM became
// HBM-refetch-bound: FETCH 240MB vs 72MB ideal (A re-streamed by 8 n-blocks),
// 305MB at the sustained 3.3TB/s = ~92us = the whole kernel. R5 proved the
// swizzle halves FETCH (98MB) -> now that BW binds, it should convert to time.
//  - block i -> XCD i%8; i = ((mg*NNB+nb)<<3)|(mb%8): all NNB n-blocks of an
//    m-stripe are dispatch-adjacent AND on one XCD; A-tile hits that L2.
// Kept: BK=64 dbuf (64KB LDS), XOR-swizzled LDS (0 conflicts),
// global_load_lds width=16 segment-contiguous staging, fused prep,
// coalesced LDS-transpose epilogue.

typedef unsigned short u16;
typedef __bf16 bf16x8 __attribute__((ext_vector_type(8)));
typedef float floatx4 __attribute__((ext_vector_type(4)));
typedef unsigned short ushort8 __attribute__((ext_vector_type(8)));

__device__ __forceinline__ u16 f2bf(float f) {
    union { float f; unsigned int u; } v; v.f = f;
    unsigned int u = v.u;
    return (u16)((u + 0x7FFFu + ((u >> 16) & 1u)) >> 16);
}

// global -> LDS direct DMA, 16 B/lane. LDS dest = wave-uniform base + lane*16.
__device__ __forceinline__ void load16(const void* g, void* l) {
    __builtin_amdgcn_global_load_lds(
        (const __attribute__((address_space(1))) void*)(unsigned long long)g,
        (__attribute__((address_space(3))) void*)(unsigned int)(unsigned long long)l,
        16, 0, 0);
}

// ---------------- fused prep: x->bf16 + 3 weight transposes ----------------
__global__ __launch_bounds__(256) void prep(
    const float* __restrict__ x, u16* __restrict__ xb,
    const float* __restrict__ W1, u16* __restrict__ w1t,
    const float* __restrict__ W2, u16* __restrict__ w2t,
    const float* __restrict__ W3, u16* __restrict__ w3t) {
    __shared__ float tile[32][33];
    int b = blockIdx.x;
    const int tid = threadIdx.x;
    if (b < 8192) {
        int i = (b * 256 + tid) * 4;
        float4 v = *(const float4*)(x + i);
        ushort4 o;
        o.x = f2bf(v.x); o.y = f2bf(v.y); o.z = f2bf(v.z); o.w = f2bf(v.w);
        *(ushort4*)(xb + i) = o;
        return;
    }
    b -= 8192;
    const float* src; u16* dst; int K, N, n0, k0, s;
    if (b < 1024) {                     // W1 [4][256][1024] -> [4][1024][256]
        s = b >> 8; int r = b & 255;
        K = 256; N = 1024; n0 = (r & 31) * 32; k0 = (r >> 5) * 32;
        src = W1; dst = w1t;
    } else if (b < 5120) {              // W2 [4][1024][1024] -> same^T
        b -= 1024; s = b >> 10; int r = b & 1023;
        K = 1024; N = 1024; n0 = (r & 31) * 32; k0 = (r >> 5) * 32;
        src = W2; dst = w2t;
    } else {                            // W3 [4][1024][512] -> [4][512][1024]
        b -= 5120; s = b >> 9; int r = b & 511;
        K = 1024; N = 512; n0 = (r & 15) * 32; k0 = (r >> 4) * 32;
        src = W3; dst = w3t;
    }
    src += (size_t)s * K * N;
    dst += (size_t)s * N * K;
    const int tx = tid & 31, ty = tid >> 5;
#pragma unroll
    for (int j = 0; j < 32; j += 8)
        tile[ty + j][tx] = src[(size_t)(k0 + ty + j) * N + (n0 + tx)];
    __syncthreads();
#pragma unroll
    for (int j = 0; j < 32; j += 8)
        dst[(size_t)(n0 + ty + j) * K + (k0 + tx)] = f2bf(tile[tx][ty + j]);
}

// ---------------- grouped GEMM: dbuf K-loop + XCD-swizzled grid ----------------
// C[m,n] = act(A[M,K] @ Wt[s][N,K]^T + bias[s][N]);  s = seps[agent(m)]
// 128x128 tile, BK=64 x2 buffers, 256 thr = 4 waves (2x2), 16x16x32 MFMA.
template <int K, int N, bool RELU, bool OUT_BF16>
__global__ __launch_bounds__(256) void gemm_mlp(
    const u16* __restrict__ Amat, const u16* __restrict__ Wt,
    const float* __restrict__ bias, const int* __restrict__ seps,
    void* __restrict__ outp) {
    constexpr int BM = 128, BN = 128, BK = 64;
    constexpr int NIT = K / BK;
    constexpr int NNB = N / 128;               // n-blocks per m-stripe (8 or 4)
    constexpr int LNB = (NNB == 8) ? 3 : 2;
    constexpr int EW = 132;                    // epilogue f32 row stride
    __shared__ u16 lds[4 * 8192];              // 64 KB: buf b at b*16384; A then B
    float* eps = (float*)lds;                  // 32x132 f32 (epilogue reuse)

    const int tid = threadIdx.x;
    const int wave = tid >> 6, lane = tid & 63;
    const int wm = wave >> 1, wn = wave & 1;
    const int quad = lane >> 4, l16 = lane & 15;

    // XCD swizzle: HW maps block i -> XCD i%8. All NNB n-blocks of one
    // m-stripe are dispatch-adjacent and share i%8 == mb%8 -> one XCD's L2
    // holds the A-stripe while all its n-blocks run concurrently there.
    const int bidx = blockIdx.x;
    const int t = bidx >> 3;
    const int mb = (t >> LNB) * 8 + (bidx & 7);
    const int nb = t & (NNB - 1);
    const int m0 = mb * BM;
    const int n0 = nb * BN;

    const int s = seps[m0 >> 12];              // 4096 rows per agent
    const u16* Ab = Amat + (size_t)m0 * K;
    const u16* Bb = Wt + ((size_t)s * N + n0) * K;

    // staging: chunk = 8 rows; lane L -> row c*8+(L>>3), k-chunk (L&7)^(L>>3)
    // -> same contiguous 128B global row segment per 8 lanes (coalesced).
    const int srow = lane >> 3;
    const int sk = ((lane & 7) ^ (lane >> 3)) * 8;

    floatx4 acc[4][4];
#pragma unroll
    for (int i = 0; i < 4; ++i)
#pragma unroll
        for (int j = 0; j < 4; ++j) acc[i][j] = (floatx4){0.f, 0.f, 0.f, 0.f};

    // prologue: stage tile 0 into buf 0
#pragma unroll
    for (int j = 0; j < 4; ++j) {
        const int c = wave * 4 + j;
        const int row = c * 8 + srow;
        load16(Ab + (size_t)row * K + sk, &lds[c * 512]);
        load16(Bb + (size_t)row * K + sk, &lds[8192 + c * 512]);
    }

    for (int it = 0; it < NIT; ++it) {
        __syncthreads();   // drains loads into buf it&1 (hidden under prev compute)
        if (it + 1 < NIT) {
            const int k0 = (it + 1) * BK;
            u16* dstb = &lds[((it + 1) & 1) * 16384];
#pragma unroll
            for (int j = 0; j < 4; ++j) {
                const int c = wave * 4 + j;
                const int row = c * 8 + srow;
                load16(Ab + (size_t)row * K + k0 + sk, dstb + c * 512);
                load16(Bb + (size_t)row * K + k0 + sk, dstb + 8192 + c * 512);
            }
        }
        const u16* smA = &lds[(it & 1) * 16384];
        const u16* smB = smA + 8192;
#pragma unroll
        for (int h = 0; h < 2; ++h) {
            const int slot = ((h * 4 + quad) ^ (l16 & 7)) * 8;
            bf16x8 af[4], bfv[4];
#pragma unroll
            for (int t2 = 0; t2 < 4; ++t2) {
                af[t2]  = *(const bf16x8*)&smA[(wm * 64 + t2 * 16 + l16) * 64 + slot];
                bfv[t2] = *(const bf16x8*)&smB[(wn * 64 + t2 * 16 + l16) * 64 + slot];
            }
#pragma unroll
            for (int mt = 0; mt < 4; ++mt)
#pragma unroll
                for (int nt = 0; nt < 4; ++nt)
                    acc[mt][nt] = __builtin_amdgcn_mfma_f32_16x16x32_bf16(
                        af[mt], bfv[nt], acc[mt][nt], 0, 0, 0);
        }
    }
    __syncthreads();   // all waves done with LDS tiles before epilogue reuse

    // ---- epilogue: 4 phases, LDS transpose, 16B/lane coalesced stores ----
    float bv[4];
#pragma unroll
    for (int nt = 0; nt < 4; ++nt)
        bv[nt] = bias[s * N + n0 + wn * 64 + nt * 16 + l16];

    const int rr = tid >> 4;      // 0..15
    const int cg = tid & 15;      // 0..15 (8 cols each)

#pragma unroll
    for (int mt = 0; mt < 4; ++mt) {
#pragma unroll
        for (int nt = 0; nt < 4; ++nt) {
#pragma unroll
            for (int r2 = 0; r2 < 4; ++r2) {
                float v = acc[mt][nt][r2] + bv[nt];
                if (RELU) v = fmaxf(v, 0.0f);
                eps[(wm * 16 + quad * 4 + r2) * EW + wn * 64 + nt * 16 + l16] = v;
            }
        }
        __syncthreads();
#pragma unroll
        for (int p = 0; p < 2; ++p) {
            const int lrow = p * 16 + rr;  // 0..31
            const int grow = m0 + ((lrow < 16) ? (mt * 16 + lrow)
                                               : (64 + mt * 16 + (lrow - 16)));
            const float* src = eps + lrow * EW + cg * 8;
            float4 v0 = *(const float4*)(src);
            float4 v1 = *(const float4*)(src + 4);
            if (OUT_BF16) {
                ushort8 o;
                o[0] = f2bf(v0.x); o[1] = f2bf(v0.y); o[2] = f2bf(v0.z); o[3] = f2bf(v0.w);
                o[4] = f2bf(v1.x); o[5] = f2bf(v1.y); o[6] = f2bf(v1.z); o[7] = f2bf(v1.w);
                *(ushort8*)((u16*)outp + (size_t)grow * N + n0 + cg * 8) = o;
            } else {
                float* dst = (float*)outp + (size_t)grow * N + n0 + cg * 8;
                *(float4*)dst = v0;
                *(float4*)(dst + 4) = v1;
            }
        }
        __syncthreads();
    }
}

extern "C" void kernel_launch(void* const* d_in, const int* in_sizes, int n_in,
                              void* d_out, int out_size, void* d_ws, size_t ws_size,
                              hipStream_t stream) {
    const float* x  = (const float*)d_in[0];
    const float* W1 = (const float*)d_in[1];
    const float* b1 = (const float*)d_in[2];
    const float* W2 = (const float*)d_in[3];
    const float* b2 = (const float*)d_in[4];
    const float* W3 = (const float*)d_in[5];
    const float* b3 = (const float*)d_in[6];
    const int* seps = (const int*)d_in[7];

    char* ws = (char*)d_ws;
    u16* w1t = (u16*)(ws);                    //  2 MB: [4][1024][256]
    u16* w2t = (u16*)(ws + (2ull << 20));     //  8 MB: [4][1024][1024]
    u16* w3t = (u16*)(ws + (10ull << 20));    //  4 MB: [4][512][1024]
    u16* xb  = (u16*)(ws + (14ull << 20));    // 16 MB: [32768][256]
    u16* h1  = (u16*)(ws + (30ull << 20));    // 64 MB: [32768][1024]
    u16* h2  = (u16*)(ws + (94ull << 20));    // 64 MB: [32768][1024]

    prep<<<15360, 256, 0, stream>>>(x, xb, W1, w1t, W2, w2t, W3, w3t);

    // L1: [32768,256]@[256,1024]^T +b1, relu -> h1 (bf16)
    gemm_mlp<256, 1024, true, true><<<2048, 256, 0, stream>>>(xb, w1t, b1, seps, h1);
    // L2: [32768,1024]@[1024,1024]^T +b2, relu -> h2 (bf16)
    gemm_mlp<1024, 1024, true, true><<<2048, 256, 0, stream>>>(h1, w2t, b2, seps, h2);
    // L3: [32768,1024]@[1024,512]^T +b3 -> out (f32)
    gemm_mlp<1024, 512, false, false><<<1024, 256, 0, stream>>>(h2, w3t, b3, seps, d_out);
}